// Round 2
// baseline (3902.831 us; speedup 1.0000x reference)
//
#include <hip/hip_runtime.h>
#include <cstddef>
#include <cstdint>

#define PI_F 3.14159265358979323846f

// ---------------------------------------------------------------------------
// Grid: per (ho, tap) fractional row and longitude-offset (px). Exact port of
// _make_grid. rows_g/dcol_g are (Ho * K2).
// ---------------------------------------------------------------------------
__global__ __launch_bounds__(256) void make_grid_kernel(
    float* __restrict__ rows_g, float* __restrict__ dcol_g,
    int Ho, int K2, int k, int H, int W, int stride, float delta)
{
    int tid = blockIdx.x * 256 + threadIdx.x;
    if (tid >= Ho * K2) return;
    int ho = tid / K2;
    int i  = tid - ho * K2;
    int jy = i / k, jx = i - jy * k;
    float half = (k - 1) * 0.5f;
    float yy = tanf(delta / (float)k * ((float)jy - half));
    float xx = tanf(delta / (float)k * ((float)jx - half));
    float rho = sqrtf(xx * xx + yy * yy);
    float rho_s = (rho == 0.f) ? 1.f : rho;
    float nu = atanf(rho);
    float lat0 = PI_F * 0.5f - ((float)(ho * stride) + 0.5f) * (PI_F / (float)H);
    float sl = sinf(lat0), cl = cosf(lat0);
    float sn = sinf(nu),  cn = cosf(nu);
    float arg = cn * sl + (yy / rho_s) * sn * cl;
    arg = fminf(1.f, fmaxf(-1.f, arg));
    float lat = asinf(arg);
    float dlon = atan2f(xx * sn, rho * cl * cn - yy * sl * sn);
    rows_g[tid] = (PI_F * 0.5f - lat) / PI_F * (float)H - 0.5f;
    dcol_g[tid] = dlon / (2.f * PI_F) * (float)W;
}

// ---------------------------------------------------------------------------
// Fused spherical-conv GEMM: Y[b][m][ho][wo] = sum_k A[m][k]*patch(n,k) + bias
// The B tile (patch values) is built in LDS by bilinear-sampling the source
// activation directly — no materialized patch matrix. Channels < C1 sample
// src1 (optionally nearest-2x upsampled via >>up1); channels >= C1 sample
// src2. This also fuses the up2+concat of the skip connections.
// Tiles: 64x64 output, K-tile 16, 256 threads, 4x4 microtile.
// ---------------------------------------------------------------------------
#define BM 64
#define BN 64
#define BK 16
#define LDP 68   // padded LDS leading dim (16B-aligned rows, conflict-free)

__global__ __launch_bounds__(256) void sconv_gemm_kernel(
    const float* __restrict__ A, const float* __restrict__ bias,
    const float* __restrict__ src1, const float* __restrict__ src2,
    int C1, int C2, int H, int W, int up1,
    const float* __restrict__ rows_g, const float* __restrict__ dcol_g,
    int K2, int stride, int lWo, int lHo,
    float* __restrict__ Y, int M, int K, int N)
{
    __shared__ float As[BK][LDP];
    __shared__ float Bs[BK][LDP];
    const int tid = threadIdx.x;
    const int n0  = blockIdx.x * BN;
    const int m0  = blockIdx.y * BM;
    const int tx  = tid & 15, ty = tid >> 4;
    const int Wo  = 1 << lWo;
    const int Ho  = 1 << lHo;
    const int HW  = 1 << (lWo + lHo);

    // This thread's fixed sampling column (B-tile build): nn constant, 4 kk's.
    const int nn    = tid & 63;
    const int kbase = tid >> 6;              // 0..3
    const int n_s   = n0 + nn;
    const bool nvalid = (n_s < N);
    const int wo_s = n_s & (Wo - 1);
    const int r_s  = n_s >> lWo;
    const int ho_s = r_s & (Ho - 1);
    const int b_s  = r_s >> lHo;
    const float* rg = rows_g + ho_s * K2;
    const float* dg = dcol_g + ho_s * K2;
    const float wo_px = (float)(wo_s * stride);
    const int Hs = H >> up1, Ws = W >> up1;

    float acc[4][4] = {};

    for (int k0 = 0; k0 < K; k0 += BK) {
        // ---- A tile: 64x16, coalesced along K ----
#pragma unroll
        for (int i = 0; i < 4; i++) {
            int idx = tid + i * 256;
            int mm = idx >> 4, kk = idx & 15;
            int m = m0 + mm, k = k0 + kk;
            As[kk][mm] = (m < M && k < K) ? A[(size_t)m * K + k] : 0.f;
        }
        // ---- B tile: bilinear gather on the fly ----
#pragma unroll
        for (int i = 0; i < 4; i++) {
            int kk = kbase + i * 4;
            int k = k0 + kk;
            float v = 0.f;
            if (nvalid && k < K) {
                int c   = k / K2;
                int tap = k - c * K2;
                float row = rg[tap];
                float col = wo_px + dg[tap];
                float r0f = floorf(row); float fr = row - r0f;
                float c0f = floorf(col); float fc = col - c0f;
                int r0  = (int)r0f;
                int r0i = min(max(r0, 0), H - 1);
                int r1i = min(max(r0 + 1, 0), H - 1);
                int c0  = (int)c0f % W; if (c0 < 0) c0 += W;
                int c1  = c0 + 1; if (c1 == W) c1 = 0;
                float v00, v01, v10, v11;
                if (c < C1) {
                    const float* p = src1 + ((size_t)b_s * C1 + c) * (size_t)(Hs * Ws);
                    int ra = r0i >> up1, rb = r1i >> up1;
                    int ca = c0 >> up1,  cb = c1 >> up1;
                    v00 = p[ra * Ws + ca]; v01 = p[ra * Ws + cb];
                    v10 = p[rb * Ws + ca]; v11 = p[rb * Ws + cb];
                } else {
                    const float* p = src2 + ((size_t)b_s * C2 + (c - C1)) * (size_t)(H * W);
                    v00 = p[r0i * W + c0]; v01 = p[r0i * W + c1];
                    v10 = p[r1i * W + c0]; v11 = p[r1i * W + c1];
                }
                v = (1.f - fr) * ((1.f - fc) * v00 + fc * v01)
                  +        fr  * ((1.f - fc) * v10 + fc * v11);
            }
            Bs[kk][nn] = v;
        }
        __syncthreads();
#pragma unroll
        for (int kk = 0; kk < BK; kk++) {
            const float4 a = *(const float4*)&As[kk][ty * 4];
            const float4 b = *(const float4*)&Bs[kk][tx * 4];
            acc[0][0] += a.x * b.x; acc[0][1] += a.x * b.y; acc[0][2] += a.x * b.z; acc[0][3] += a.x * b.w;
            acc[1][0] += a.y * b.x; acc[1][1] += a.y * b.y; acc[1][2] += a.y * b.z; acc[1][3] += a.y * b.w;
            acc[2][0] += a.z * b.x; acc[2][1] += a.z * b.y; acc[2][2] += a.z * b.z; acc[2][3] += a.z * b.w;
            acc[3][0] += a.w * b.x; acc[3][1] += a.w * b.y; acc[3][2] += a.w * b.z; acc[3][3] += a.w * b.w;
        }
        __syncthreads();
    }

#pragma unroll
    for (int i = 0; i < 4; i++) {
        int m = m0 + ty * 4 + i;
        if (m >= M) continue;
        float bv = bias[m];
#pragma unroll
        for (int j = 0; j < 4; j++) {
            int n = n0 + tx * 4 + j;
            if (n >= N) continue;
            int wo = n & (Wo - 1);
            int r  = n >> lWo;
            int ho = r & (Ho - 1);
            int b_ = r >> lHo;
            Y[((size_t)b_ * M + m) * HW + (ho << lWo) + wo] = acc[i][j] + bv;
        }
    }
}

// ---------------------------------------------------------------------------
// BN stats: one block per channel; mean + biased var over (B, Ho, Wo).
// ---------------------------------------------------------------------------
__global__ __launch_bounds__(256) void bn_stats_kernel(
    const float* __restrict__ Y, float* __restrict__ stats,
    int Co, int HW, int B)
{
    int co = blockIdx.x;
    int tid = threadIdx.x;
    int Nt = B * HW;
    double s = 0.0, s2 = 0.0;
    for (int idx = tid; idx < Nt; idx += 256) {
        int b = idx / HW; int sp = idx - b * HW;
        float v = Y[((size_t)b * Co + co) * HW + sp];
        s += v; s2 += (double)v * v;
    }
    __shared__ double sh_s[256], sh_s2[256];
    sh_s[tid] = s; sh_s2[tid] = s2;
    __syncthreads();
    for (int off = 128; off > 0; off >>= 1) {
        if (tid < off) { sh_s[tid] += sh_s[tid + off]; sh_s2[tid] += sh_s2[tid + off]; }
        __syncthreads();
    }
    if (tid == 0) {
        double mean = sh_s[0] / Nt;
        double var = sh_s2[0] / Nt - mean * mean;
        if (var < 0.0) var = 0.0;
        stats[co * 2]     = (float)mean;
        stats[co * 2 + 1] = (float)var;
    }
}

__global__ __launch_bounds__(256) void bn_apply_kernel(
    float* __restrict__ Y, const float* __restrict__ stats,
    const float* __restrict__ g, const float* __restrict__ bb,
    int Co, int HW, int total)
{
    int idx = blockIdx.x * 256 + threadIdx.x;
    if (idx >= total) return;
    int c = (idx / HW) % Co;
    float mean = stats[c * 2], var = stats[c * 2 + 1];
    float sc = g[c] / sqrtf(var + 1e-5f);
    float sf = bb[c] - mean * sc;
    float v = Y[idx] * sc + sf;
    Y[idx] = v > 0.f ? v : 0.f;
}

// ---------------------------------------------------------------------------
// Host orchestration. Workspace footprint (floats):
//   stats 512 + grids ~14K + x2 (2.10M) + x31 (1.05M) + scratch Q (4.19M)
//   = ~7.36M floats = ~29.5 MB. All writes provably within d_ws.
// Scratch Q reuse by lifetime: x1=Q+0 (L1-2), x3=Q+0 (L3-4), x4=Q+0 (L5-6),
//   x41=Q+512K (L6-7), x5=Q+1M (L7-8). No overlap of live ranges.
// ---------------------------------------------------------------------------
extern "C" void kernel_launch(void* const* d_in, const int* in_sizes, int n_in,
                              void* d_out, int out_size, void* d_ws, size_t ws_size,
                              hipStream_t stream)
{
    const int B = 4;
    float* ws = (float*)d_ws;
    size_t off = 0;
    auto alloc = [&](size_t n) -> float* {
        float* p = ws + off;
        off += (n + 63) & ~(size_t)63;
        return p;
    };

    float* stats = alloc(512);

    // grid buffers per layer
    static const int kH[8]  = {256, 128, 64, 32, 32, 16, 32, 64};
    static const int kW[8]  = {512, 256, 128, 64, 64, 32, 64, 128};
    static const int kK[8]  = {7, 5, 5, 3, 3, 3, 3, 3};
    static const int kSt[8] = {2, 2, 2, 1, 2, 1, 1, 1};
    float* rows_g[8]; float* dcol_g[8];
    for (int i = 0; i < 8; i++) {
        int Ho = kH[i] / kSt[i];
        int K2 = kK[i] * kK[i];
        rows_g[i] = alloc((size_t)Ho * K2);
        dcol_g[i] = alloc((size_t)Ho * K2);
    }

    float* x2  = alloc((size_t)B * 64  * 64 * 128);   // persists L2..L8
    float* x31 = alloc((size_t)B * 128 * 32 * 64);    // persists L4..L7
    float* Q   = alloc((size_t)B * 32  * 128 * 256);  // shared scratch (4.19M)
    float* x1  = Q;                                   // L1-2
    float* x3  = Q;                                   // L3-4 (x1 dead)
    float* x4  = Q;                                   // L5-6 (x3 dead)
    float* x41 = Q + (size_t)B * 256 * 16 * 32;       // L6-7 (disjoint from x4)
    float* x5  = Q + 2 * (size_t)B * 256 * 16 * 32;   // L7-8 (disjoint from x41)
    (void)ws_size; (void)in_sizes; (void)n_in; (void)out_size;

    struct LCfg { const float *s1, *s2; int C1, C2, up; float delta; int widx, Cout; float* Y; };
    const float* input = (const float*)d_in[0];
    LCfg L[8] = {
        { input, nullptr,   6,   0, 0, PI_F / 32.f,  1,  32, x1  },
        { x1,    nullptr,  32,   0, 0, PI_F / 16.f,  5,  64, x2  },
        { x2,    nullptr,  64,   0, 0, PI_F / 4.f,   9, 128, x3  },
        { x3,    nullptr, 128,   0, 0, PI_F / 4.f,  13, 128, x31 },
        { x31,   nullptr, 128,   0, 0, PI_F / 2.f,  17, 256, x4  },
        { x4,    nullptr, 256,   0, 0, PI_F / 2.f,  21, 256, x41 },
        { x41,   x31,     256, 128, 1, PI_F / 4.f,  25, 256, x5  },
        { x5,    x2,      256,  64, 1, PI_F / 8.f,  29, 128, (float*)d_out },
    };

    for (int i = 0; i < 8; i++) {
        const LCfg& c = L[i];
        int H = kH[i], W = kW[i], k = kK[i], st = kSt[i];
        int Ho = H / st, Wo = W / st;
        int K2 = k * k;
        int K  = (c.C1 + c.C2) * K2;
        int HW = Ho * Wo;
        int N  = B * HW;
        int lWo = __builtin_ctz(Wo), lHo = __builtin_ctz(Ho);
        const float* Wt   = (const float*)d_in[c.widx];
        const float* bias = (const float*)d_in[c.widx + 1];
        const float* gam  = (const float*)d_in[c.widx + 2];
        const float* bet  = (const float*)d_in[c.widx + 3];

        int gn = Ho * K2;
        make_grid_kernel<<<dim3((gn + 255) / 256), dim3(256), 0, stream>>>(
            rows_g[i], dcol_g[i], Ho, K2, k, H, W, st, c.delta);

        dim3 mgrid((N + BN - 1) / BN, (c.Cout + BM - 1) / BM);
        sconv_gemm_kernel<<<mgrid, dim3(256), 0, stream>>>(
            Wt, bias, c.s1, c.s2, c.C1, c.C2, H, W, c.up,
            rows_g[i], dcol_g[i], K2, st, lWo, lHo,
            c.Y, c.Cout, K, N);

        bn_stats_kernel<<<dim3(c.Cout), dim3(256), 0, stream>>>(c.Y, stats, c.Cout, HW, B);
        int total = B * c.Cout * HW;
        bn_apply_kernel<<<dim3((total + 255) / 256), dim3(256), 0, stream>>>(
            c.Y, stats, gam, bet, c.Cout, HW, total);
    }
}